// Round 1
// baseline (4854.836 us; speedup 1.0000x reference)
//
#include <hip/hip_runtime.h>

#define NSTEP 16
#define BATCH 65536
#define DD 64
#define HH 256
#define MT 32           // rows per block (halved: 4 blocks/CU, no spills)
#define H0S 264         // padded LDS stride (elems) for 256-wide activations
#define ABSTR 72        // padded LDS stride (elems) for 64-wide layer0 input

typedef _Float16 half8 __attribute__((ext_vector_type(8)));
typedef float floatx4 __attribute__((ext_vector_type(4)));

// ---------------- prep: transpose + fp16-cast weights into d_ws ----------------
// ws layout (elems): Wt0 [256][64] @ 0 ; Wt1 [256][256] @ 16384 ; Wt2 [64][256] @ 81920
__global__ __launch_bounds__(256) void prep_weights(
    const float* __restrict__ W0, const float* __restrict__ W1,
    const float* __restrict__ W2, _Float16* __restrict__ ws)
{
    int i = blockIdx.x * 256 + threadIdx.x;      // 0..65535 (256 blocks!)
    _Float16* Wt0 = ws;
    _Float16* Wt1 = ws + 16384;
    _Float16* Wt2 = ws + 16384 + 65536;
    { int n = i >> 8, k = i & 255; Wt1[i] = (_Float16)W1[k * HH + n]; }
    if (i < 16384) {
        { int n = i >> 6, k = i & 63;  Wt0[i] = (_Float16)W0[k * HH + n]; }
        { int n = i >> 8, k = i & 255; Wt2[i] = (_Float16)W2[k * DD + n]; }
    }
}

// ---------------- one MLP forward (or masked-JVP forward) ----------------
// A-frag: A[m=lane&15][k=quad*8+j]; B-frag: B[k=quad*8+j][n=lane&15];
// C/D:    col=lane&15, row=quad*4+reg  (guide-verified layouts, 16x16x32)
// MT=32: 2 row-tiles (rt<2) instead of 4.
template<bool MASKED>
__device__ __forceinline__ void mlp_pass(
    const _Float16* __restrict__ Wt0, const _Float16* __restrict__ Wt1,
    const _Float16* __restrict__ Wt2,
    const float* __restrict__ b1g, const float* __restrict__ b2g,
    _Float16* h0, _Float16* h1, const _Float16* ab, const float* c0buf,
    int wave, int quad, int l16, float* outv)
{
    const floatx4 zero4 = {0.f, 0.f, 0.f, 0.f};

    // ---------- layer 0: [32x64] @ [64x256] ----------
    floatx4 acc[2][4];
#pragma unroll
    for (int rt = 0; rt < 2; rt++)
#pragma unroll
        for (int ct = 0; ct < 4; ct++) acc[rt][ct] = zero4;
#pragma unroll
    for (int kc = 0; kc < 2; kc++) {
        half8 af[2], bf[4];
#pragma unroll
        for (int rt = 0; rt < 2; rt++)
            af[rt] = *(const half8*)(ab + (rt * 16 + l16) * ABSTR + kc * 32 + quad * 8);
#pragma unroll
        for (int ct = 0; ct < 4; ct++)
            bf[ct] = *(const half8*)(Wt0 + (wave * 64 + ct * 16 + l16) * DD + kc * 32 + quad * 8);
#pragma unroll
        for (int rt = 0; rt < 2; rt++)
#pragma unroll
            for (int ct = 0; ct < 4; ct++)
                acc[rt][ct] = __builtin_amdgcn_mfma_f32_16x16x32_f16(af[rt], bf[ct], acc[rt][ct], 0, 0, 0);
    }
#pragma unroll
    for (int ct = 0; ct < 4; ct++) {
        int col = wave * 64 + ct * 16 + l16;
        float cb = MASKED ? 0.f : c0buf[col];
#pragma unroll
        for (int rt = 0; rt < 2; rt++)
#pragma unroll
            for (int rr = 0; rr < 4; rr++) {
                int row = rt * 16 + quad * 4 + rr;
                float v = acc[rt][ct][rr];
                if (MASKED) {
                    float z = (float)h0[row * H0S + col];   // relu(z0) from base pass (same lane wrote it)
                    h0[row * H0S + col] = (_Float16)(z > 0.f ? v : 0.f);
                } else {
                    v += cb;
                    h0[row * H0S + col] = (_Float16)(v > 0.f ? v : 0.f);
                }
            }
    }
    __syncthreads();

    // ---------- layer 1: [32x256] @ [256x256] ----------
#pragma unroll
    for (int rt = 0; rt < 2; rt++)
#pragma unroll
        for (int ct = 0; ct < 4; ct++) acc[rt][ct] = zero4;
#pragma unroll
    for (int kc = 0; kc < 8; kc++) {
        half8 af[2], bf[4];
#pragma unroll
        for (int rt = 0; rt < 2; rt++)
            af[rt] = *(const half8*)(h0 + (rt * 16 + l16) * H0S + kc * 32 + quad * 8);
#pragma unroll
        for (int ct = 0; ct < 4; ct++)
            bf[ct] = *(const half8*)(Wt1 + (wave * 64 + ct * 16 + l16) * HH + kc * 32 + quad * 8);
#pragma unroll
        for (int rt = 0; rt < 2; rt++)
#pragma unroll
            for (int ct = 0; ct < 4; ct++)
                acc[rt][ct] = __builtin_amdgcn_mfma_f32_16x16x32_f16(af[rt], bf[ct], acc[rt][ct], 0, 0, 0);
    }
#pragma unroll
    for (int ct = 0; ct < 4; ct++) {
        int col = wave * 64 + ct * 16 + l16;
        float cb = MASKED ? 0.f : b1g[col];
#pragma unroll
        for (int rt = 0; rt < 2; rt++)
#pragma unroll
            for (int rr = 0; rr < 4; rr++) {
                int row = rt * 16 + quad * 4 + rr;
                float v = acc[rt][ct][rr];
                if (MASKED) {
                    float z = (float)h1[row * H0S + col];
                    h1[row * H0S + col] = (_Float16)(z > 0.f ? v : 0.f);
                } else {
                    v += cb;
                    h1[row * H0S + col] = (_Float16)(v > 0.f ? v : 0.f);
                }
            }
    }
    __syncthreads();

    // ---------- layer 2: [32x256] @ [256x64] ----------
    floatx4 a2[2];
#pragma unroll
    for (int rt = 0; rt < 2; rt++) a2[rt] = zero4;
#pragma unroll
    for (int kc = 0; kc < 8; kc++) {
        half8 bf2 = *(const half8*)(Wt2 + (wave * 16 + l16) * HH + kc * 32 + quad * 8);
#pragma unroll
        for (int rt = 0; rt < 2; rt++) {
            half8 af = *(const half8*)(h1 + (rt * 16 + l16) * H0S + kc * 32 + quad * 8);
            a2[rt] = __builtin_amdgcn_mfma_f32_16x16x32_f16(af, bf2, a2[rt], 0, 0, 0);
        }
    }
    float bb2 = MASKED ? 0.f : b2g[wave * 16 + l16];
#pragma unroll
    for (int rt = 0; rt < 2; rt++)
#pragma unroll
        for (int rr = 0; rr < 4; rr++) outv[rt * 4 + rr] = a2[rt][rr] + bb2;
    // no trailing sync; callers separate buffer reuse with their own syncs
}

// ---------------- main: 32 rows per block, full 16-step integration ----------------
// launch_bounds(256,4): cap 128 VGPR = 4 waves/SIMD; LDS ~39.5KB = 4 blocks/CU.
__global__ __launch_bounds__(256, 4) void ffjord_kernel(
    const float* __restrict__ xg, const float* __restrict__ epsg,
    const float* __restrict__ W0g, const float* __restrict__ b0g,
    const float* __restrict__ b1g, const float* __restrict__ b2g,
    const _Float16* __restrict__ ws, float* __restrict__ out)
{
    __shared__ __attribute__((aligned(16))) _Float16 h0[MT * H0S];
    __shared__ __attribute__((aligned(16))) _Float16 h1[MT * H0S];
    __shared__ __attribute__((aligned(16))) _Float16 ab[MT * ABSTR];
    __shared__ float c0buf[HH];
    __shared__ float ldacc[MT];

    const _Float16* Wt0 = ws;
    const _Float16* Wt1 = ws + 16384;
    const _Float16* Wt2 = ws + 16384 + 65536;

    const int tid  = threadIdx.x;
    const int wave = tid >> 6;
    const int lane = tid & 63;
    const int quad = lane >> 4;
    const int l16  = lane & 15;
    const int row0 = blockIdx.x * MT;
    const int colD = wave * 16 + l16;          // this lane's state column (layer-2 C layout)
    const float dt = 1.f / NSTEP;

    if (tid < MT) ldacc[tid] = 0.f;

    // per-lane state: 32 rows x 64 cols / 256 threads = 8 values
    float x[8];
#pragma unroll
    for (int i = 0; i < 8; i++) {
        int r = (i >> 2) * 16 + quad * 4 + (i & 3);
        x[i] = xg[(size_t)(row0 + r) * DD + colD];
    }

#pragma unroll 1
    for (int s = 0; s < NSTEP; s++) {
        float t = s * dt;
        float e[8];
#pragma unroll
        for (int i = 0; i < 8; i++) {
            int r = (i >> 2) * 16 + quad * 4 + (i & 3);
            e[i] = epsg[(size_t)(s * BATCH + row0 + r) * DD + colD];
        }
        float xacc[8], kprev[8], yv[8], outv[8];
#pragma unroll
        for (int i = 0; i < 8; i++) { xacc[i] = x[i]; kprev[i] = 0.f; }

        // pass order: 0=base(k1), 1=jvp, 2=k2, 3=k3, 4=k4
#pragma unroll 1
        for (int p = 0; p < 5; p++) {
            if (p == 1) {
                // analytic JVP: v = 0.5*e through masked-linear network
#pragma unroll
                for (int i = 0; i < 8; i++) yv[i] = 0.5f * e[i];
#pragma unroll
                for (int i = 0; i < 8; i++) {
                    int r = (i >> 2) * 16 + quad * 4 + (i & 3);
                    ab[r * ABSTR + colD] = (_Float16)yv[i];
                }
                __syncthreads();
                mlp_pass<true>(Wt0, Wt1, Wt2, b1g, b2g, h0, h1, ab, c0buf,
                               wave, quad, l16, outv);
                // trace = sum_col e * (0.5e + dMLP); ld -= trace*dt
#pragma unroll
                for (int i = 0; i < 8; i++) {
                    float pr = e[i] * (0.5f * e[i] + outv[i]);
                    pr += __shfl_xor(pr, 1);
                    pr += __shfl_xor(pr, 2);
                    pr += __shfl_xor(pr, 4);
                    pr += __shfl_xor(pr, 8);
                    if (l16 == 0) {
                        int r = (i >> 2) * 16 + quad * 4 + (i & 3);
                        atomicAdd(&ldacc[r], -dt * pr);
                    }
                }
            } else {
                float c  = (p == 4) ? 1.f : 0.5f;                 // y = x + c*dt*kprev (kprev=0 at p==0)
                float w  = (p == 0 || p == 4) ? dt / 6.f : dt / 3.f;
                float tp = t + ((p == 4) ? dt : (p >= 2 ? 0.5f * dt : 0.f));
#pragma unroll
                for (int i = 0; i < 8; i++) yv[i] = x[i] + c * dt * kprev[i];
#pragma unroll
                for (int i = 0; i < 8; i++) {
                    int r = (i >> 2) * 16 + quad * 4 + (i & 3);
                    ab[r * ABSTR + colD] = (_Float16)yv[i];
                }
                // c0 = t*W0[t-row] + b0 folds the time feature (layer0 runs K=64)
                c0buf[tid] = tp * W0g[64 * HH + tid] + b0g[tid];
                __syncthreads();
                mlp_pass<false>(Wt0, Wt1, Wt2, b1g, b2g, h0, h1, ab, c0buf,
                                wave, quad, l16, outv);
#pragma unroll
                for (int i = 0; i < 8; i++) {
                    kprev[i] = yv[i] + outv[i];                   // k = y + MLP(y)  (residual)
                    xacc[i] += w * kprev[i];
                }
            }
        }
#pragma unroll
        for (int i = 0; i < 8; i++) x[i] = xacc[i];
    }

    // outputs: x_out [B,D] then log_det [B]
#pragma unroll
    for (int i = 0; i < 8; i++) {
        int r = (i >> 2) * 16 + quad * 4 + (i & 3);
        out[(size_t)(row0 + r) * DD + colD] = x[i];
    }
    __syncthreads();
    if (tid < MT) out[(size_t)BATCH * DD + row0 + tid] = ldacc[tid];
}

extern "C" void kernel_launch(void* const* d_in, const int* in_sizes, int n_in,
                              void* d_out, int out_size, void* d_ws, size_t ws_size,
                              hipStream_t stream) {
    const float* xg   = (const float*)d_in[0];
    const float* epsg = (const float*)d_in[1];
    const float* W0g  = (const float*)d_in[2];
    const float* b0g  = (const float*)d_in[3];
    const float* W1g  = (const float*)d_in[4];
    const float* b1g  = (const float*)d_in[5];
    const float* W2g  = (const float*)d_in[6];
    const float* b2g  = (const float*)d_in[7];
    float* outp = (float*)d_out;
    _Float16* ws = (_Float16*)d_ws;

    prep_weights<<<65536 / 256, 256, 0, stream>>>(W0g, W1g, W2g, ws);
    ffjord_kernel<<<BATCH / MT, 256, 0, stream>>>(xg, epsg, W0g, b0g, b1g, b2g, ws, outp);
}

// Round 2
// 4844.978 us; speedup vs baseline: 1.0020x; 1.0020x over previous
//
#include <hip/hip_runtime.h>

#define NSTEP 16
#define BATCH 65536
#define DD 64
#define HH 256
#define MT 32           // rows per block: LDS ~39.9KB -> 4 blocks/CU
#define H0S 264         // padded LDS stride (elems) for 256-wide activations
#define ABSTR 72        // padded LDS stride (elems) for 64-wide layer0 input

typedef _Float16 half8 __attribute__((ext_vector_type(8)));
typedef float floatx4 __attribute__((ext_vector_type(4)));

// ---------------- prep: transpose + fp16-cast weights into d_ws ----------------
// ws layout (elems): Wt0 [256][64] @ 0 ; Wt1 [256][256] @ 16384 ; Wt2 [64][256] @ 81920
__global__ __launch_bounds__(256) void prep_weights(
    const float* __restrict__ W0, const float* __restrict__ W1,
    const float* __restrict__ W2, _Float16* __restrict__ ws)
{
    int i = blockIdx.x * 256 + threadIdx.x;      // 0..65535 (256 blocks!)
    _Float16* Wt0 = ws;
    _Float16* Wt1 = ws + 16384;
    _Float16* Wt2 = ws + 16384 + 65536;
    { int n = i >> 8, k = i & 255; Wt1[i] = (_Float16)W1[k * HH + n]; }
    if (i < 16384) {
        { int n = i >> 6, k = i & 63;  Wt0[i] = (_Float16)W0[k * HH + n]; }
        { int n = i >> 8, k = i & 255; Wt2[i] = (_Float16)W2[k * DD + n]; }
    }
}

// ---------------- one MLP forward (or masked-JVP forward) ----------------
// A-frag: A[m=lane&15][k=quad*8+j]; B-frag: B[k=quad*8+j][n=lane&15];
// C/D:    col=lane&15, row=quad*4+reg  (guide-verified layouts, 16x16x32)
// MT=32: 2 row-tiles (rt<2).
template<bool MASKED>
__device__ __forceinline__ void mlp_pass(
    const _Float16* __restrict__ Wt0, const _Float16* __restrict__ Wt1,
    const _Float16* __restrict__ Wt2,
    const float* __restrict__ b1g, const float* __restrict__ b2g,
    _Float16* h0, _Float16* h1, const _Float16* ab, const float* c0buf,
    int wave, int quad, int l16, float* outv)
{
    const floatx4 zero4 = {0.f, 0.f, 0.f, 0.f};

    // ---------- layer 0: [32x64] @ [64x256] ----------
    floatx4 acc[2][4];
#pragma unroll
    for (int rt = 0; rt < 2; rt++)
#pragma unroll
        for (int ct = 0; ct < 4; ct++) acc[rt][ct] = zero4;
#pragma unroll
    for (int kc = 0; kc < 2; kc++) {
        half8 af[2], bf[4];
#pragma unroll
        for (int rt = 0; rt < 2; rt++)
            af[rt] = *(const half8*)(ab + (rt * 16 + l16) * ABSTR + kc * 32 + quad * 8);
#pragma unroll
        for (int ct = 0; ct < 4; ct++)
            bf[ct] = *(const half8*)(Wt0 + (wave * 64 + ct * 16 + l16) * DD + kc * 32 + quad * 8);
#pragma unroll
        for (int rt = 0; rt < 2; rt++)
#pragma unroll
            for (int ct = 0; ct < 4; ct++)
                acc[rt][ct] = __builtin_amdgcn_mfma_f32_16x16x32_f16(af[rt], bf[ct], acc[rt][ct], 0, 0, 0);
    }
#pragma unroll
    for (int ct = 0; ct < 4; ct++) {
        int col = wave * 64 + ct * 16 + l16;
        float cb = MASKED ? 0.f : c0buf[col];
#pragma unroll
        for (int rt = 0; rt < 2; rt++)
#pragma unroll
            for (int rr = 0; rr < 4; rr++) {
                int row = rt * 16 + quad * 4 + rr;
                float v = acc[rt][ct][rr];
                if (MASKED) {
                    float z = (float)h0[row * H0S + col];   // relu(z0) from base pass (same lane wrote it)
                    h0[row * H0S + col] = (_Float16)(z > 0.f ? v : 0.f);
                } else {
                    v += cb;
                    h0[row * H0S + col] = (_Float16)(v > 0.f ? v : 0.f);
                }
            }
    }
    __syncthreads();

    // ---------- layer 1: [32x256] @ [256x256] ----------
#pragma unroll
    for (int rt = 0; rt < 2; rt++)
#pragma unroll
        for (int ct = 0; ct < 4; ct++) acc[rt][ct] = zero4;
#pragma unroll
    for (int kc = 0; kc < 8; kc++) {
        half8 af[2], bf[4];
#pragma unroll
        for (int rt = 0; rt < 2; rt++)
            af[rt] = *(const half8*)(h0 + (rt * 16 + l16) * H0S + kc * 32 + quad * 8);
#pragma unroll
        for (int ct = 0; ct < 4; ct++)
            bf[ct] = *(const half8*)(Wt1 + (wave * 64 + ct * 16 + l16) * HH + kc * 32 + quad * 8);
#pragma unroll
        for (int rt = 0; rt < 2; rt++)
#pragma unroll
            for (int ct = 0; ct < 4; ct++)
                acc[rt][ct] = __builtin_amdgcn_mfma_f32_16x16x32_f16(af[rt], bf[ct], acc[rt][ct], 0, 0, 0);
    }
#pragma unroll
    for (int ct = 0; ct < 4; ct++) {
        int col = wave * 64 + ct * 16 + l16;
        float cb = MASKED ? 0.f : b1g[col];
#pragma unroll
        for (int rt = 0; rt < 2; rt++)
#pragma unroll
            for (int rr = 0; rr < 4; rr++) {
                int row = rt * 16 + quad * 4 + rr;
                float v = acc[rt][ct][rr];
                if (MASKED) {
                    float z = (float)h1[row * H0S + col];
                    h1[row * H0S + col] = (_Float16)(z > 0.f ? v : 0.f);
                } else {
                    v += cb;
                    h1[row * H0S + col] = (_Float16)(v > 0.f ? v : 0.f);
                }
            }
    }
    __syncthreads();

    // ---------- layer 2: [32x256] @ [256x64] ----------
    floatx4 a2[2];
#pragma unroll
    for (int rt = 0; rt < 2; rt++) a2[rt] = zero4;
#pragma unroll
    for (int kc = 0; kc < 8; kc++) {
        half8 bf2 = *(const half8*)(Wt2 + (wave * 16 + l16) * HH + kc * 32 + quad * 8);
#pragma unroll
        for (int rt = 0; rt < 2; rt++) {
            half8 af = *(const half8*)(h1 + (rt * 16 + l16) * H0S + kc * 32 + quad * 8);
            a2[rt] = __builtin_amdgcn_mfma_f32_16x16x32_f16(af, bf2, a2[rt], 0, 0, 0);
        }
    }
    float bb2 = MASKED ? 0.f : b2g[wave * 16 + l16];
#pragma unroll
    for (int rt = 0; rt < 2; rt++)
#pragma unroll
        for (int rr = 0; rr < 4; rr++) outv[rt * 4 + rr] = a2[rt][rr] + bb2;
    // no trailing sync; callers separate buffer reuse with their own syncs
}

// ---------------- main: 32 rows per block, full 16-step integration ----------------
// amdgpu_waves_per_eu(4,4): pin allocator to the 128-VGPR tier (4 waves/EU).
// R1 lesson: launch_bounds(256,4) alone let the allocator squeeze to 64 VGPR
// (8 waves/EU target) -> ~50 spilled regs -> FETCH_SIZE 4.85GB of scratch fills.
__global__ __launch_bounds__(256) __attribute__((amdgpu_waves_per_eu(4, 4)))
void ffjord_kernel(
    const float* __restrict__ xg, const float* __restrict__ epsg,
    const float* __restrict__ W0g, const float* __restrict__ b0g,
    const float* __restrict__ b1g, const float* __restrict__ b2g,
    const _Float16* __restrict__ ws, float* __restrict__ out)
{
    __shared__ __attribute__((aligned(16))) _Float16 h0[MT * H0S];
    __shared__ __attribute__((aligned(16))) _Float16 h1[MT * H0S];
    __shared__ __attribute__((aligned(16))) _Float16 ab[MT * ABSTR];
    __shared__ float c0buf[HH];
    __shared__ float ldacc[MT];

    const _Float16* Wt0 = ws;
    const _Float16* Wt1 = ws + 16384;
    const _Float16* Wt2 = ws + 16384 + 65536;

    const int tid  = threadIdx.x;
    const int wave = tid >> 6;
    const int lane = tid & 63;
    const int quad = lane >> 4;
    const int l16  = lane & 15;
    const int row0 = blockIdx.x * MT;
    const int colD = wave * 16 + l16;          // this lane's state column (layer-2 C layout)
    const float dt = 1.f / NSTEP;

    if (tid < MT) ldacc[tid] = 0.f;

    // per-lane state: 32 rows x 64 cols / 256 threads = 8 values
    float x[8];
#pragma unroll
    for (int i = 0; i < 8; i++) {
        int r = (i >> 2) * 16 + quad * 4 + (i & 3);
        x[i] = xg[(size_t)(row0 + r) * DD + colD];
    }

#pragma unroll 1
    for (int s = 0; s < NSTEP; s++) {
        float t = s * dt;
        float e[8];
#pragma unroll
        for (int i = 0; i < 8; i++) {
            int r = (i >> 2) * 16 + quad * 4 + (i & 3);
            e[i] = epsg[(size_t)(s * BATCH + row0 + r) * DD + colD];
        }
        float xacc[8], kprev[8], yv[8], outv[8];
#pragma unroll
        for (int i = 0; i < 8; i++) { xacc[i] = x[i]; kprev[i] = 0.f; }

        // pass order: 0=base(k1), 1=jvp, 2=k2, 3=k3, 4=k4
#pragma unroll 1
        for (int p = 0; p < 5; p++) {
            if (p == 1) {
                // analytic JVP: v = 0.5*e through masked-linear network
#pragma unroll
                for (int i = 0; i < 8; i++) yv[i] = 0.5f * e[i];
#pragma unroll
                for (int i = 0; i < 8; i++) {
                    int r = (i >> 2) * 16 + quad * 4 + (i & 3);
                    ab[r * ABSTR + colD] = (_Float16)yv[i];
                }
                __syncthreads();
                mlp_pass<true>(Wt0, Wt1, Wt2, b1g, b2g, h0, h1, ab, c0buf,
                               wave, quad, l16, outv);
                // trace = sum_col e * (0.5e + dMLP); ld -= trace*dt
#pragma unroll
                for (int i = 0; i < 8; i++) {
                    float pr = e[i] * (0.5f * e[i] + outv[i]);
                    pr += __shfl_xor(pr, 1);
                    pr += __shfl_xor(pr, 2);
                    pr += __shfl_xor(pr, 4);
                    pr += __shfl_xor(pr, 8);
                    if (l16 == 0) {
                        int r = (i >> 2) * 16 + quad * 4 + (i & 3);
                        atomicAdd(&ldacc[r], -dt * pr);
                    }
                }
            } else {
                float c  = (p == 4) ? 1.f : 0.5f;                 // y = x + c*dt*kprev (kprev=0 at p==0)
                float w  = (p == 0 || p == 4) ? dt / 6.f : dt / 3.f;
                float tp = t + ((p == 4) ? dt : (p >= 2 ? 0.5f * dt : 0.f));
#pragma unroll
                for (int i = 0; i < 8; i++) yv[i] = x[i] + c * dt * kprev[i];
#pragma unroll
                for (int i = 0; i < 8; i++) {
                    int r = (i >> 2) * 16 + quad * 4 + (i & 3);
                    ab[r * ABSTR + colD] = (_Float16)yv[i];
                }
                // c0 = t*W0[t-row] + b0 folds the time feature (layer0 runs K=64)
                c0buf[tid] = tp * W0g[64 * HH + tid] + b0g[tid];
                __syncthreads();
                mlp_pass<false>(Wt0, Wt1, Wt2, b1g, b2g, h0, h1, ab, c0buf,
                                wave, quad, l16, outv);
#pragma unroll
                for (int i = 0; i < 8; i++) {
                    kprev[i] = yv[i] + outv[i];                   // k = y + MLP(y)  (residual)
                    xacc[i] += w * kprev[i];
                }
            }
        }
#pragma unroll
        for (int i = 0; i < 8; i++) x[i] = xacc[i];
    }

    // outputs: x_out [B,D] then log_det [B]
#pragma unroll
    for (int i = 0; i < 8; i++) {
        int r = (i >> 2) * 16 + quad * 4 + (i & 3);
        out[(size_t)(row0 + r) * DD + colD] = x[i];
    }
    __syncthreads();
    if (tid < MT) out[(size_t)BATCH * DD + row0 + tid] = ldacc[tid];
}

extern "C" void kernel_launch(void* const* d_in, const int* in_sizes, int n_in,
                              void* d_out, int out_size, void* d_ws, size_t ws_size,
                              hipStream_t stream) {
    const float* xg   = (const float*)d_in[0];
    const float* epsg = (const float*)d_in[1];
    const float* W0g  = (const float*)d_in[2];
    const float* b0g  = (const float*)d_in[3];
    const float* W1g  = (const float*)d_in[4];
    const float* b1g  = (const float*)d_in[5];
    const float* W2g  = (const float*)d_in[6];
    const float* b2g  = (const float*)d_in[7];
    float* outp = (float*)d_out;
    _Float16* ws = (_Float16*)d_ws;

    prep_weights<<<65536 / 256, 256, 0, stream>>>(W0g, W1g, W2g, ws);
    ffjord_kernel<<<BATCH / MT, 256, 0, stream>>>(xg, epsg, W0g, b0g, b1g, b2g, ws, outp);
}

// Round 3
// 3863.808 us; speedup vs baseline: 1.2565x; 1.2539x over previous
//
#include <hip/hip_runtime.h>

#define NSTEP 16
#define BATCH 65536
#define DD 64
#define HH 256
#define MT 32           // rows per block: LDS ~39.9KB -> 4 blocks/CU
#define H0S 264         // padded LDS stride (elems) for 256-wide activations
#define ABSTR 72        // padded LDS stride (elems) for 64-wide layer0 input

typedef _Float16 half8 __attribute__((ext_vector_type(8)));
typedef float floatx4 __attribute__((ext_vector_type(4)));

// ---------------- prep: transpose + fp16-cast weights into d_ws ----------------
// ws layout (elems): Wt0 [256][64] @ 0 ; Wt1 [256][256] @ 16384 ; Wt2 [64][256] @ 81920
__global__ __launch_bounds__(256) void prep_weights(
    const float* __restrict__ W0, const float* __restrict__ W1,
    const float* __restrict__ W2, _Float16* __restrict__ ws)
{
    int i = blockIdx.x * 256 + threadIdx.x;      // 0..65535 (256 blocks!)
    _Float16* Wt0 = ws;
    _Float16* Wt1 = ws + 16384;
    _Float16* Wt2 = ws + 16384 + 65536;
    { int n = i >> 8, k = i & 255; Wt1[i] = (_Float16)W1[k * HH + n]; }
    if (i < 16384) {
        { int n = i >> 6, k = i & 63;  Wt0[i] = (_Float16)W0[k * HH + n]; }
        { int n = i >> 8, k = i & 255; Wt2[i] = (_Float16)W2[k * DD + n]; }
    }
}

// ---------------- one MLP forward (or masked-JVP forward) ----------------
// A-frag: A[m=lane&15][k=quad*8+j]; B-frag: B[k=quad*8+j][n=lane&15];
// C/D:    col=lane&15, row=quad*4+reg  (guide-verified layouts, 16x16x32)
// MT=32: 2 row-tiles (rt<2).
template<bool MASKED>
__device__ __forceinline__ void mlp_pass(
    const _Float16* __restrict__ Wt0, const _Float16* __restrict__ Wt1,
    const _Float16* __restrict__ Wt2,
    const float* __restrict__ b1g, const float* __restrict__ b2g,
    _Float16* h0, _Float16* h1, const _Float16* ab, const float* c0buf,
    int wave, int quad, int l16, float* outv)
{
    const floatx4 zero4 = {0.f, 0.f, 0.f, 0.f};

    // ---------- layer 0: [32x64] @ [64x256] ----------
    floatx4 acc[2][4];
#pragma unroll
    for (int rt = 0; rt < 2; rt++)
#pragma unroll
        for (int ct = 0; ct < 4; ct++) acc[rt][ct] = zero4;
#pragma unroll
    for (int kc = 0; kc < 2; kc++) {
        half8 af[2], bf[4];
#pragma unroll
        for (int rt = 0; rt < 2; rt++)
            af[rt] = *(const half8*)(ab + (rt * 16 + l16) * ABSTR + kc * 32 + quad * 8);
#pragma unroll
        for (int ct = 0; ct < 4; ct++)
            bf[ct] = *(const half8*)(Wt0 + (wave * 64 + ct * 16 + l16) * DD + kc * 32 + quad * 8);
#pragma unroll
        for (int rt = 0; rt < 2; rt++)
#pragma unroll
            for (int ct = 0; ct < 4; ct++)
                acc[rt][ct] = __builtin_amdgcn_mfma_f32_16x16x32_f16(af[rt], bf[ct], acc[rt][ct], 0, 0, 0);
    }
#pragma unroll
    for (int ct = 0; ct < 4; ct++) {
        int col = wave * 64 + ct * 16 + l16;
        float cb = MASKED ? 0.f : c0buf[col];
#pragma unroll
        for (int rt = 0; rt < 2; rt++)
#pragma unroll
            for (int rr = 0; rr < 4; rr++) {
                int row = rt * 16 + quad * 4 + rr;
                float v = acc[rt][ct][rr];
                if (MASKED) {
                    float z = (float)h0[row * H0S + col];   // relu(z0) from base pass (same lane wrote it)
                    h0[row * H0S + col] = (_Float16)(z > 0.f ? v : 0.f);
                } else {
                    v += cb;
                    h0[row * H0S + col] = (_Float16)(v > 0.f ? v : 0.f);
                }
            }
    }
    __syncthreads();

    // ---------- layer 1: [32x256] @ [256x256] ----------
#pragma unroll
    for (int rt = 0; rt < 2; rt++)
#pragma unroll
        for (int ct = 0; ct < 4; ct++) acc[rt][ct] = zero4;
#pragma unroll
    for (int kc = 0; kc < 8; kc++) {
        half8 af[2], bf[4];
#pragma unroll
        for (int rt = 0; rt < 2; rt++)
            af[rt] = *(const half8*)(h0 + (rt * 16 + l16) * H0S + kc * 32 + quad * 8);
#pragma unroll
        for (int ct = 0; ct < 4; ct++)
            bf[ct] = *(const half8*)(Wt1 + (wave * 64 + ct * 16 + l16) * HH + kc * 32 + quad * 8);
#pragma unroll
        for (int rt = 0; rt < 2; rt++)
#pragma unroll
            for (int ct = 0; ct < 4; ct++)
                acc[rt][ct] = __builtin_amdgcn_mfma_f32_16x16x32_f16(af[rt], bf[ct], acc[rt][ct], 0, 0, 0);
    }
#pragma unroll
    for (int ct = 0; ct < 4; ct++) {
        int col = wave * 64 + ct * 16 + l16;
        float cb = MASKED ? 0.f : b1g[col];
#pragma unroll
        for (int rt = 0; rt < 2; rt++)
#pragma unroll
            for (int rr = 0; rr < 4; rr++) {
                int row = rt * 16 + quad * 4 + rr;
                float v = acc[rt][ct][rr];
                if (MASKED) {
                    float z = (float)h1[row * H0S + col];
                    h1[row * H0S + col] = (_Float16)(z > 0.f ? v : 0.f);
                } else {
                    v += cb;
                    h1[row * H0S + col] = (_Float16)(v > 0.f ? v : 0.f);
                }
            }
    }
    __syncthreads();

    // ---------- layer 2: [32x256] @ [256x64] ----------
    floatx4 a2[2];
#pragma unroll
    for (int rt = 0; rt < 2; rt++) a2[rt] = zero4;
#pragma unroll
    for (int kc = 0; kc < 8; kc++) {
        half8 bf2 = *(const half8*)(Wt2 + (wave * 16 + l16) * HH + kc * 32 + quad * 8);
#pragma unroll
        for (int rt = 0; rt < 2; rt++) {
            half8 af = *(const half8*)(h1 + (rt * 16 + l16) * H0S + kc * 32 + quad * 8);
            a2[rt] = __builtin_amdgcn_mfma_f32_16x16x32_f16(af, bf2, a2[rt], 0, 0, 0);
        }
    }
    float bb2 = MASKED ? 0.f : b2g[wave * 16 + l16];
#pragma unroll
    for (int rt = 0; rt < 2; rt++)
#pragma unroll
        for (int rr = 0; rr < 4; rr++) outv[rt * 4 + rr] = a2[rt][rr] + bb2;
    // no trailing sync; callers separate buffer reuse with their own syncs
}

// ---------------- main: 32 rows per block, full 16-step integration ----------------
// __launch_bounds__(256, 2): R0/R1 evidence says this toolchain's allocator lands
// one occupancy tier ABOVE the declared min (min=2 -> 128 VGPR, min=4 -> 64 VGPR).
// Declare 2, get the 128-VGPR tier; LDS (39.9KB) still pins 4 blocks/CU = 16 waves/CU.
// yv[] eliminated (recomputed at both use sites) to pull peak pressure under 128.
__global__ __launch_bounds__(256, 2) void ffjord_kernel(
    const float* __restrict__ xg, const float* __restrict__ epsg,
    const float* __restrict__ W0g, const float* __restrict__ b0g,
    const float* __restrict__ b1g, const float* __restrict__ b2g,
    const _Float16* __restrict__ ws, float* __restrict__ out)
{
    __shared__ __attribute__((aligned(16))) _Float16 h0[MT * H0S];
    __shared__ __attribute__((aligned(16))) _Float16 h1[MT * H0S];
    __shared__ __attribute__((aligned(16))) _Float16 ab[MT * ABSTR];
    __shared__ float c0buf[HH];
    __shared__ float ldacc[MT];

    const _Float16* Wt0 = ws;
    const _Float16* Wt1 = ws + 16384;
    const _Float16* Wt2 = ws + 16384 + 65536;

    const int tid  = threadIdx.x;
    const int wave = tid >> 6;
    const int lane = tid & 63;
    const int quad = lane >> 4;
    const int l16  = lane & 15;
    const int row0 = blockIdx.x * MT;
    const int colD = wave * 16 + l16;          // this lane's state column (layer-2 C layout)
    const float dt = 1.f / NSTEP;

    if (tid < MT) ldacc[tid] = 0.f;

    // per-lane state: 32 rows x 64 cols / 256 threads = 8 values
    float x[8];
#pragma unroll
    for (int i = 0; i < 8; i++) {
        int r = (i >> 2) * 16 + quad * 4 + (i & 3);
        x[i] = xg[(size_t)(row0 + r) * DD + colD];
    }

#pragma unroll 1
    for (int s = 0; s < NSTEP; s++) {
        float t = s * dt;
        float e[8];
#pragma unroll
        for (int i = 0; i < 8; i++) {
            int r = (i >> 2) * 16 + quad * 4 + (i & 3);
            e[i] = epsg[(size_t)(s * BATCH + row0 + r) * DD + colD];
        }
        float xacc[8], kprev[8], outv[8];
#pragma unroll
        for (int i = 0; i < 8; i++) { xacc[i] = x[i]; kprev[i] = 0.f; }

        // pass order: 0=base(k1), 1=jvp, 2=k2, 3=k3, 4=k4
#pragma unroll 1
        for (int p = 0; p < 5; p++) {
            if (p == 1) {
                // analytic JVP: v = 0.5*e through masked-linear network
#pragma unroll
                for (int i = 0; i < 8; i++) {
                    int r = (i >> 2) * 16 + quad * 4 + (i & 3);
                    ab[r * ABSTR + colD] = (_Float16)(0.5f * e[i]);
                }
                __syncthreads();
                mlp_pass<true>(Wt0, Wt1, Wt2, b1g, b2g, h0, h1, ab, c0buf,
                               wave, quad, l16, outv);
                // trace = sum_col e * (0.5e + dMLP); ld -= trace*dt
#pragma unroll
                for (int i = 0; i < 8; i++) {
                    float pr = e[i] * (0.5f * e[i] + outv[i]);
                    pr += __shfl_xor(pr, 1);
                    pr += __shfl_xor(pr, 2);
                    pr += __shfl_xor(pr, 4);
                    pr += __shfl_xor(pr, 8);
                    if (l16 == 0) {
                        int r = (i >> 2) * 16 + quad * 4 + (i & 3);
                        atomicAdd(&ldacc[r], -dt * pr);
                    }
                }
            } else {
                float c  = (p == 4) ? 1.f : 0.5f;                 // y = x + c*dt*kprev (kprev=0 at p==0)
                float w  = (p == 0 || p == 4) ? dt / 6.f : dt / 3.f;
                float tp = t + ((p == 4) ? dt : (p >= 2 ? 0.5f * dt : 0.f));
                // y recomputed at both use sites (no persistent yv[] -> -8 VGPR at peak)
#pragma unroll
                for (int i = 0; i < 8; i++) {
                    int r = (i >> 2) * 16 + quad * 4 + (i & 3);
                    ab[r * ABSTR + colD] = (_Float16)(x[i] + c * dt * kprev[i]);
                }
                // c0 = t*W0[t-row] + b0 folds the time feature (layer0 runs K=64)
                c0buf[tid] = tp * W0g[64 * HH + tid] + b0g[tid];
                __syncthreads();
                mlp_pass<false>(Wt0, Wt1, Wt2, b1g, b2g, h0, h1, ab, c0buf,
                                wave, quad, l16, outv);
#pragma unroll
                for (int i = 0; i < 8; i++) {
                    kprev[i] = x[i] + c * dt * kprev[i] + outv[i]; // k = y + MLP(y)  (residual)
                    xacc[i] += w * kprev[i];
                }
            }
        }
#pragma unroll
        for (int i = 0; i < 8; i++) x[i] = xacc[i];
    }

    // outputs: x_out [B,D] then log_det [B]
#pragma unroll
    for (int i = 0; i < 8; i++) {
        int r = (i >> 2) * 16 + quad * 4 + (i & 3);
        out[(size_t)(row0 + r) * DD + colD] = x[i];
    }
    __syncthreads();
    if (tid < MT) out[(size_t)BATCH * DD + row0 + tid] = ldacc[tid];
}

extern "C" void kernel_launch(void* const* d_in, const int* in_sizes, int n_in,
                              void* d_out, int out_size, void* d_ws, size_t ws_size,
                              hipStream_t stream) {
    const float* xg   = (const float*)d_in[0];
    const float* epsg = (const float*)d_in[1];
    const float* W0g  = (const float*)d_in[2];
    const float* b0g  = (const float*)d_in[3];
    const float* W1g  = (const float*)d_in[4];
    const float* b1g  = (const float*)d_in[5];
    const float* W2g  = (const float*)d_in[6];
    const float* b2g  = (const float*)d_in[7];
    float* outp = (float*)d_out;
    _Float16* ws = (_Float16*)d_ws;

    prep_weights<<<65536 / 256, 256, 0, stream>>>(W0g, W1g, W2g, ws);
    ffjord_kernel<<<BATCH / MT, 256, 0, stream>>>(xg, epsg, W0g, b0g, b1g, b2g, ws, outp);
}

// Round 5
// 2732.951 us; speedup vs baseline: 1.7764x; 1.4138x over previous
//
#include <hip/hip_runtime.h>

#define NSTEP 16
#define BATCH 65536
#define DD 64
#define HH 256
#define MT 64           // rows per block (fat waves: 128 MFMA/wave/pass, best row-throughput)
#define H0S 264         // padded LDS stride (elems) for 256-wide activations
#define ABSTR 72        // padded LDS stride (elems) for 64-wide layer0 input

typedef _Float16 half8 __attribute__((ext_vector_type(8)));
typedef float floatx4 __attribute__((ext_vector_type(4)));

// ---------------- prep: transpose + fp16-cast weights into d_ws ----------------
// ws layout (elems): Wt0 [256][64] @ 0 ; Wt1 [256][256] @ 16384 ; Wt2 [64][256] @ 81920
__global__ __launch_bounds__(256) void prep_weights(
    const float* __restrict__ W0, const float* __restrict__ W1,
    const float* __restrict__ W2, _Float16* __restrict__ ws)
{
    int i = blockIdx.x * 256 + threadIdx.x;      // 0..65535 (256 blocks!)
    _Float16* Wt0 = ws;
    _Float16* Wt1 = ws + 16384;
    _Float16* Wt2 = ws + 16384 + 65536;
    { int n = i >> 8, k = i & 255; Wt1[i] = (_Float16)W1[k * HH + n]; }
    if (i < 16384) {
        { int n = i >> 6, k = i & 63;  Wt0[i] = (_Float16)W0[k * HH + n]; }
        { int n = i >> 8, k = i & 255; Wt2[i] = (_Float16)W2[k * DD + n]; }
    }
}

// ---------------- one MLP forward (or masked-JVP forward) ----------------
// A-frag: A[m=lane&15][k=quad*8+j]; B-frag: B[k=quad*8+j][n=lane&15];
// C/D:    col=lane&15, row=quad*4+reg  (guide-verified layouts, 16x16x32)
// Layer0/2 B-fragments come from persistent registers (w0f/w2f, hoisted per block).
template<bool MASKED>
__device__ __forceinline__ void mlp_pass(
    const half8 (&w0f)[2][4], const _Float16* __restrict__ Wt1,
    const half8 (&w2f)[8], const float (&b1v)[4], float bb2,
    _Float16* h0, _Float16* h1, const _Float16* ab, const float* c0buf,
    int wave, int quad, int l16, float* outv)
{
    const floatx4 zero4 = {0.f, 0.f, 0.f, 0.f};

    // ---------- layer 0: [64x64] @ [64x256], B from registers ----------
    floatx4 acc[4][4];
#pragma unroll
    for (int rt = 0; rt < 4; rt++)
#pragma unroll
        for (int ct = 0; ct < 4; ct++) acc[rt][ct] = zero4;
#pragma unroll
    for (int kc = 0; kc < 2; kc++) {
        half8 af[4];
#pragma unroll
        for (int rt = 0; rt < 4; rt++)
            af[rt] = *(const half8*)(ab + (rt * 16 + l16) * ABSTR + kc * 32 + quad * 8);
#pragma unroll
        for (int rt = 0; rt < 4; rt++)
#pragma unroll
            for (int ct = 0; ct < 4; ct++)
                acc[rt][ct] = __builtin_amdgcn_mfma_f32_16x16x32_f16(af[rt], w0f[kc][ct], acc[rt][ct], 0, 0, 0);
    }
#pragma unroll
    for (int ct = 0; ct < 4; ct++) {
        int col = wave * 64 + ct * 16 + l16;
        float cb = MASKED ? 0.f : c0buf[col];
#pragma unroll
        for (int rt = 0; rt < 4; rt++)
#pragma unroll
            for (int rr = 0; rr < 4; rr++) {
                int row = rt * 16 + quad * 4 + rr;
                float v = acc[rt][ct][rr];
                if (MASKED) {
                    float z = (float)h0[row * H0S + col];   // relu(z0) from base pass (same lane wrote it)
                    h0[row * H0S + col] = (_Float16)(z > 0.f ? v : 0.f);
                } else {
                    v += cb;
                    h0[row * H0S + col] = (_Float16)(v > 0.f ? v : 0.f);
                }
            }
    }
    __syncthreads();

    // ---------- layer 1: [64x256] @ [256x256], B streamed from L2 ----------
#pragma unroll
    for (int rt = 0; rt < 4; rt++)
#pragma unroll
        for (int ct = 0; ct < 4; ct++) acc[rt][ct] = zero4;
#pragma unroll
    for (int kc = 0; kc < 8; kc++) {
        half8 af[4], bf[4];
#pragma unroll
        for (int rt = 0; rt < 4; rt++)
            af[rt] = *(const half8*)(h0 + (rt * 16 + l16) * H0S + kc * 32 + quad * 8);
#pragma unroll
        for (int ct = 0; ct < 4; ct++)
            bf[ct] = *(const half8*)(Wt1 + (wave * 64 + ct * 16 + l16) * HH + kc * 32 + quad * 8);
#pragma unroll
        for (int rt = 0; rt < 4; rt++)
#pragma unroll
            for (int ct = 0; ct < 4; ct++)
                acc[rt][ct] = __builtin_amdgcn_mfma_f32_16x16x32_f16(af[rt], bf[ct], acc[rt][ct], 0, 0, 0);
    }
#pragma unroll
    for (int ct = 0; ct < 4; ct++) {
        int col = wave * 64 + ct * 16 + l16;
        float cb = MASKED ? 0.f : b1v[ct];
#pragma unroll
        for (int rt = 0; rt < 4; rt++)
#pragma unroll
            for (int rr = 0; rr < 4; rr++) {
                int row = rt * 16 + quad * 4 + rr;
                float v = acc[rt][ct][rr];
                if (MASKED) {
                    float z = (float)h1[row * H0S + col];
                    h1[row * H0S + col] = (_Float16)(z > 0.f ? v : 0.f);
                } else {
                    v += cb;
                    h1[row * H0S + col] = (_Float16)(v > 0.f ? v : 0.f);
                }
            }
    }
    __syncthreads();

    // ---------- layer 2: [64x256] @ [256x64], B from registers ----------
    floatx4 a2[4];
#pragma unroll
    for (int rt = 0; rt < 4; rt++) a2[rt] = zero4;
#pragma unroll
    for (int kc = 0; kc < 8; kc++) {
#pragma unroll
        for (int rt = 0; rt < 4; rt++) {
            half8 af = *(const half8*)(h1 + (rt * 16 + l16) * H0S + kc * 32 + quad * 8);
            a2[rt] = __builtin_amdgcn_mfma_f32_16x16x32_f16(af, w2f[kc], a2[rt], 0, 0, 0);
        }
    }
    float bb = MASKED ? 0.f : bb2;
#pragma unroll
    for (int rt = 0; rt < 4; rt++)
#pragma unroll
        for (int rr = 0; rr < 4; rr++) outv[rt * 4 + rr] = a2[rt][rr] + bb;
    // no trailing sync; callers separate buffer reuse with their own syncs
}

// ---------------- main: 64 rows per block, full 16-step integration ----------------
// __launch_bounds__(256, 1): allocator model (R0/R1/R3) says it targets the
// 2*min waves/SIMD tier -> min=1 gives the 256-reg budget. LDS (78KB) caps at
// 2 blocks/CU regardless, so the relaxed bound costs no occupancy.
// Wt0/Wt2 fragments + biases hoisted to persistent registers (reused 80x/block);
// eps is re-read from L2 at trace time instead of staying live through passes.
__global__ __launch_bounds__(256, 1) void ffjord_kernel(
    const float* __restrict__ xg, const float* __restrict__ epsg,
    const float* __restrict__ W0g, const float* __restrict__ b0g,
    const float* __restrict__ b1g, const float* __restrict__ b2g,
    const _Float16* __restrict__ ws, float* __restrict__ out)
{
    __shared__ __attribute__((aligned(16))) _Float16 h0[MT * H0S];
    __shared__ __attribute__((aligned(16))) _Float16 h1[MT * H0S];
    __shared__ __attribute__((aligned(16))) _Float16 ab[MT * ABSTR];
    __shared__ float c0buf[HH];
    __shared__ float ldacc[MT];

    const _Float16* Wt0 = ws;
    const _Float16* Wt1 = ws + 16384;
    const _Float16* Wt2 = ws + 16384 + 65536;

    const int tid  = threadIdx.x;
    const int wave = tid >> 6;
    const int lane = tid & 63;
    const int quad = lane >> 4;
    const int l16  = lane & 15;
    const int row0 = blockIdx.x * MT;
    const int colD = wave * 16 + l16;          // this lane's state column (layer-2 C layout)
    const float dt = 1.f / NSTEP;

    if (tid < MT) ldacc[tid] = 0.f;

    // ---- persistent register-resident weights (loaded once, reused 80 passes) ----
    half8 w0f[2][4];                            // layer0 B-frags: 32 VGPR
#pragma unroll
    for (int kc = 0; kc < 2; kc++)
#pragma unroll
        for (int ct = 0; ct < 4; ct++)
            w0f[kc][ct] = *(const half8*)(Wt0 + (wave * 64 + ct * 16 + l16) * DD + kc * 32 + quad * 8);
    half8 w2f[8];                               // layer2 B-frags: 32 VGPR
#pragma unroll
    for (int kc = 0; kc < 8; kc++)
        w2f[kc] = *(const half8*)(Wt2 + (wave * 16 + l16) * HH + kc * 32 + quad * 8);
    float b1v[4];
#pragma unroll
    for (int ct = 0; ct < 4; ct++) b1v[ct] = b1g[wave * 64 + ct * 16 + l16];
    const float bb2 = b2g[wave * 16 + l16];
    const float w0t = W0g[64 * HH + tid];       // time-row of W0 (for c0buf)
    const float b0v = b0g[tid];

    // per-lane state: 64 rows x 64 cols / 256 threads = 16 values
    float x[16];
#pragma unroll
    for (int i = 0; i < 16; i++) {
        int r = (i >> 2) * 16 + quad * 4 + (i & 3);
        x[i] = xg[(size_t)(row0 + r) * DD + colD];
    }

#pragma unroll 1
    for (int s = 0; s < NSTEP; s++) {
        float t = s * dt;
        float xacc[16], kprev[16], outv[16];
#pragma unroll
        for (int i = 0; i < 16; i++) { xacc[i] = x[i]; kprev[i] = 0.f; }

        // pass order: 0=base(k1), 1=jvp, 2=k2, 3=k3, 4=k4
#pragma unroll 1
        for (int p = 0; p < 5; p++) {
            if (p == 1) {
                // analytic JVP: v = 0.5*e through masked-linear network.
                // eps loaded, consumed into ab, then RELOADED after the pass
                // (keeps 16 regs dead across the layer1 pressure peak).
#pragma unroll
                for (int i = 0; i < 16; i++) {
                    int r = (i >> 2) * 16 + quad * 4 + (i & 3);
                    float ev = epsg[(size_t)(s * BATCH + row0 + r) * DD + colD];
                    ab[r * ABSTR + colD] = (_Float16)(0.5f * ev);
                }
                __syncthreads();
                mlp_pass<true>(w0f, Wt1, w2f, b1v, bb2, h0, h1, ab, c0buf,
                               wave, quad, l16, outv);
                // trace = sum_col e * (0.5e + dMLP); ld -= trace*dt
#pragma unroll
                for (int i = 0; i < 16; i++) {
                    int r = (i >> 2) * 16 + quad * 4 + (i & 3);
                    float ev = epsg[(size_t)(s * BATCH + row0 + r) * DD + colD];
                    float pr = ev * (0.5f * ev + outv[i]);
                    pr += __shfl_xor(pr, 1);
                    pr += __shfl_xor(pr, 2);
                    pr += __shfl_xor(pr, 4);
                    pr += __shfl_xor(pr, 8);
                    if (l16 == 0) atomicAdd(&ldacc[r], -dt * pr);
                }
            } else {
                float c  = (p == 4) ? 1.f : 0.5f;                 // y = x + c*dt*kprev (kprev=0 at p==0)
                float w  = (p == 0 || p == 4) ? dt / 6.f : dt / 3.f;
                float tp = t + ((p == 4) ? dt : (p >= 2 ? 0.5f * dt : 0.f));
                // y recomputed at both use sites (no persistent yv[])
#pragma unroll
                for (int i = 0; i < 16; i++) {
                    int r = (i >> 2) * 16 + quad * 4 + (i & 3);
                    ab[r * ABSTR + colD] = (_Float16)(x[i] + c * dt * kprev[i]);
                }
                // c0 = t*W0[t-row] + b0 folds the time feature (layer0 runs K=64)
                c0buf[tid] = tp * w0t + b0v;
                __syncthreads();
                mlp_pass<false>(w0f, Wt1, w2f, b1v, bb2, h0, h1, ab, c0buf,
                                wave, quad, l16, outv);
#pragma unroll
                for (int i = 0; i < 16; i++) {
                    kprev[i] = x[i] + c * dt * kprev[i] + outv[i]; // k = y + MLP(y)  (residual)
                    xacc[i] += w * kprev[i];
                }
            }
        }
#pragma unroll
        for (int i = 0; i < 16; i++) x[i] = xacc[i];
    }

    // outputs: x_out [B,D] then log_det [B]
#pragma unroll
    for (int i = 0; i < 16; i++) {
        int r = (i >> 2) * 16 + quad * 4 + (i & 3);
        out[(size_t)(row0 + r) * DD + colD] = x[i];
    }
    __syncthreads();
    if (tid < MT) out[(size_t)BATCH * DD + row0 + tid] = ldacc[tid];
}

extern "C" void kernel_launch(void* const* d_in, const int* in_sizes, int n_in,
                              void* d_out, int out_size, void* d_ws, size_t ws_size,
                              hipStream_t stream) {
    const float* xg   = (const float*)d_in[0];
    const float* epsg = (const float*)d_in[1];
    const float* W0g  = (const float*)d_in[2];
    const float* b0g  = (const float*)d_in[3];
    const float* W1g  = (const float*)d_in[4];
    const float* b1g  = (const float*)d_in[5];
    const float* W2g  = (const float*)d_in[6];
    const float* b2g  = (const float*)d_in[7];
    float* outp = (float*)d_out;
    _Float16* ws = (_Float16*)d_ws;

    prep_weights<<<65536 / 256, 256, 0, stream>>>(W0g, W1g, W2g, ws);
    ffjord_kernel<<<BATCH / MT, 256, 0, stream>>>(xg, epsg, W0g, b0g, b1g, b2g, ws, outp);
}